// Round 1
// baseline (180.456 us; speedup 1.0000x reference)
//
#include <hip/hip_runtime.h>
#include <hip/hip_bf16.h>

// ---------------- problem constants ----------------
#define EPS 1e-5f
#define SLOPE 0.01f

// workspace layout (float element offsets)
#define WS_WVS 0                         // WvS transposed [c][n] : 2048*16
#define WS_BVS 32768                     // bvS[16]
#define WS_QK  32800                     // qk[1024][2048] : cols 0..1023 = q, 1024..2047 = k
#define WS_ATT (WS_QK + 1024*2048)       // att[1024][16]
#define WS_S   (WS_ATT + 1024*16)        // S[1024][16]

// ---------------- kernel 0: prep WvS (v-row sums of Wkv) + bvS ----------------
__global__ __launch_bounds__(256) void prep_kernel(
        const float* __restrict__ Wkv, const float* __restrict__ bkv,
        float* __restrict__ ws) {
    int gid = blockIdx.x * 256 + threadIdx.x;   // 0..32767
    int n = gid >> 11;                          // head 0..15
    int c = gid & 2047;                         // input col
    const float* base = Wkv + (size_t)(n * 128 + 64) * 2048 + c;
    float s = 0.f;
    #pragma unroll 8
    for (int d = 0; d < 64; ++d) s += base[(size_t)d * 2048];
    ws[WS_WVS + c * 16 + n] = s;                // store transposed [c][n]
    if (gid < 16) {
        float b = 0.f;
        #pragma unroll
        for (int d = 0; d < 64; ++d) b += bkv[gid * 128 + 64 + d];
        ws[WS_BVS + gid] = b;
    }
}

// ---------------- kernel 1: fused q / k projection GEMM ----------------
// Output qk[1024][2048]: col j<1024 : q[b][j]  = q_input[b]·Wq[j] + bq[j]
//                        col 1024+j2: k[b][n,d]= kv_input[b]·Wkv[n*128+d] + bkv[n*128+d]
// Tile: 64 rows x 128 cols, 256 threads, microtile 4x8, KT=16, reg-prefetch dbuf.
#define TM 64
#define TN 128
#define KT 16

__global__ __launch_bounds__(256) void gemm_qk_kernel(
        const float* __restrict__ qin, const float* __restrict__ kvin,
        const float* __restrict__ Wq, const float* __restrict__ Wkv,
        const float* __restrict__ bq, const float* __restrict__ bkv,
        float* __restrict__ qk) {
    __shared__ float As[KT][TM];    // [k][m]
    __shared__ float Bs[KT][TN];    // [k][n]

    int t  = threadIdx.x;
    int n0 = blockIdx.x * TN;       // output col base (0..1920)
    int m0 = blockIdx.y * TM;       // output row base
    bool is_k = (n0 >= 1024);
    const float* Ain = is_k ? kvin : qin;

    // staging addresses
    int arow = t >> 2;              // 0..63
    int akk  = (t & 3) * 4;         // 0,4,8,12
    const float* aptr = Ain + (size_t)(m0 + arow) * 2048 + akk;

    int brow0 = t >> 2;             // 0..63
    int brow1 = 64 + (t >> 2);      // 64..127
    int bkk   = (t & 3) * 4;
    auto wptr = [&](int brow) -> const float* {
        int j = n0 + brow;
        if (!is_k) return Wq + (size_t)j * 2048 + bkk;
        int j2 = j - 1024;
        int r = ((j2 >> 6) << 7) + (j2 & 63);   // head*128 + d
        return Wkv + (size_t)r * 2048 + bkk;
    };
    const float* bptr0 = wptr(brow0);
    const float* bptr1 = wptr(brow1);

    int tx = t & 15;                // col group: cols tx*4..+3 and 64+tx*4..+3
    int ty = t >> 4;                // row group: rows ty*4..+3

    float acc[4][8];
    #pragma unroll
    for (int i = 0; i < 4; ++i)
        #pragma unroll
        for (int j = 0; j < 8; ++j) acc[i][j] = 0.f;

    float4 ra  = *(const float4*)aptr;
    float4 rb0 = *(const float4*)bptr0;
    float4 rb1 = *(const float4*)bptr1;

    for (int s = 0; s < 2048 / KT; ++s) {
        // regs -> LDS (transposed scatter)
        As[akk + 0][arow] = ra.x;  As[akk + 1][arow] = ra.y;
        As[akk + 2][arow] = ra.z;  As[akk + 3][arow] = ra.w;
        Bs[bkk + 0][brow0] = rb0.x; Bs[bkk + 1][brow0] = rb0.y;
        Bs[bkk + 2][brow0] = rb0.z; Bs[bkk + 3][brow0] = rb0.w;
        Bs[bkk + 0][brow1] = rb1.x; Bs[bkk + 1][brow1] = rb1.y;
        Bs[bkk + 2][brow1] = rb1.z; Bs[bkk + 3][brow1] = rb1.w;
        __syncthreads();
        if (s < 2048 / KT - 1) {    // prefetch next stage (overlaps compute)
            ra  = *(const float4*)(aptr  + (size_t)(s + 1) * KT);
            rb0 = *(const float4*)(bptr0 + (size_t)(s + 1) * KT);
            rb1 = *(const float4*)(bptr1 + (size_t)(s + 1) * KT);
        }
        #pragma unroll
        for (int kk = 0; kk < KT; ++kk) {
            float4 a  = *(const float4*)&As[kk][ty * 4];
            float4 b0 = *(const float4*)&Bs[kk][tx * 4];
            float4 b1 = *(const float4*)&Bs[kk][64 + tx * 4];
            float av[4] = {a.x, a.y, a.z, a.w};
            float bv[8] = {b0.x, b0.y, b0.z, b0.w, b1.x, b1.y, b1.z, b1.w};
            #pragma unroll
            for (int i = 0; i < 4; ++i)
                #pragma unroll
                for (int j = 0; j < 8; ++j)
                    acc[i][j] = fmaf(av[i], bv[j], acc[i][j]);
        }
        __syncthreads();
    }

    // epilogue: + bias, store
    float bias[8];
    #pragma unroll
    for (int j = 0; j < 8; ++j) {
        int col = n0 + ((j < 4) ? (tx * 4 + j) : (64 + tx * 4 + (j - 4)));
        if (!is_k) bias[j] = bq[col];
        else { int j2 = col - 1024; bias[j] = bkv[((j2 >> 6) << 7) + (j2 & 63)]; }
    }
    #pragma unroll
    for (int i = 0; i < 4; ++i) {
        int row = m0 + ty * 4 + i;
        float4 o;
        o.x = acc[i][0] + bias[0]; o.y = acc[i][1] + bias[1];
        o.z = acc[i][2] + bias[2]; o.w = acc[i][3] + bias[3];
        *(float4*)(qk + (size_t)row * 2048 + n0 + tx * 4) = o;
        o.x = acc[i][4] + bias[4]; o.y = acc[i][5] + bias[5];
        o.z = acc[i][6] + bias[6]; o.w = acc[i][7] + bias[7];
        *(float4*)(qk + (size_t)row * 2048 + n0 + 64 + tx * 4) = o;
    }
}

// ---------------- kernel 2: sim -> softmax(att) ; S = kv_input @ WvS.T + bvS ----------------
// one block (256 thr = 4 waves) per sample b
__global__ __launch_bounds__(256) void attn_kernel(
        const float* __restrict__ kvin, float* __restrict__ ws) {
    int b = blockIdx.x;
    int t = threadIdx.x;
    int w = t >> 6;
    int l = t & 63;
    __shared__ float sims[16];
    __shared__ float SW[4][16];

    const float* qrow = ws + WS_QK + (size_t)b * 2048;
    // --- sim[b,h] = q[b,h,:]·k[b,h,:] : wave w covers heads 4w..4w+3
    {
        float4 q4 = *(const float4*)(qrow + w * 256 + l * 4);
        float4 k4 = *(const float4*)(qrow + 1024 + w * 256 + l * 4);
        float p = q4.x * k4.x + q4.y * k4.y + q4.z * k4.z + q4.w * k4.w;
        p += __shfl_xor(p, 1);
        p += __shfl_xor(p, 2);
        p += __shfl_xor(p, 4);
        p += __shfl_xor(p, 8);
        if ((l & 15) == 0) sims[w * 4 + (l >> 4)] = p;
    }
    // --- S[b,n] partial: thread (g=t>>4, n=t&15) strides columns
    {
        int n = t & 15;
        int g = t >> 4;
        const float* kvrow = kvin + (size_t)b * 2048;
        const float* wv = ws + WS_WVS;
        float p = 0.f;
        #pragma unroll 4
        for (int tt = 0; tt < 128; ++tt) {
            int c = g + (tt << 4);
            p = fmaf(kvrow[c], wv[c * 16 + n], p);
        }
        p += __shfl_xor(p, 16);   // reduce over g within wave
        p += __shfl_xor(p, 32);
        if (l < 16) SW[w][n] = p;
    }
    __syncthreads();
    if (t < 16) {
        float sv = SW[0][t] + SW[1][t] + SW[2][t] + SW[3][t] + ws[WS_BVS + t];
        ws[WS_S + b * 16 + t] = sv;
        float m = sims[0];
        #pragma unroll
        for (int n2 = 1; n2 < 16; ++n2) m = fmaxf(m, sims[n2]);
        float den = 0.f;
        #pragma unroll
        for (int n2 = 0; n2 < 16; ++n2) den += expf(sims[n2] - m);
        ws[WS_ATT + b * 16 + t] = expf(sims[t] - m) / den;
    }
}

// ---------------- kernel 3: A-reduce, pooled, leaky, batchnorm, output ----------------
// single block, 1024 threads (thread i = sample i)
__global__ __launch_bounds__(1024) void final_kernel(
        const float* __restrict__ bn_w, const float* __restrict__ bn_b,
        const float* __restrict__ Wo, const float* __restrict__ bo,
        const float* __restrict__ ws, float* __restrict__ out) {
    int t = threadIdx.x;
    int w = t >> 6;
    int l = t & 63;
    __shared__ float Aw[16][16];
    __shared__ float Af[4][16];
    __shared__ float SWs[16][8];
    __shared__ float FS[8];
    __shared__ float sc[4], sh[4];

    // A[f,n] = sum of att rows in chunk f (chunk = 4 consecutive waves)
    float a16[16];
    {
        const float* arow = ws + WS_ATT + (size_t)t * 16;
        float4 v0 = *(const float4*)(arow + 0);
        float4 v1 = *(const float4*)(arow + 4);
        float4 v2 = *(const float4*)(arow + 8);
        float4 v3 = *(const float4*)(arow + 12);
        a16[0]=v0.x; a16[1]=v0.y; a16[2]=v0.z; a16[3]=v0.w;
        a16[4]=v1.x; a16[5]=v1.y; a16[6]=v1.z; a16[7]=v1.w;
        a16[8]=v2.x; a16[9]=v2.y; a16[10]=v2.z; a16[11]=v2.w;
        a16[12]=v3.x; a16[13]=v3.y; a16[14]=v3.z; a16[15]=v3.w;
    }
    #pragma unroll
    for (int n = 0; n < 16; ++n) {
        float p = a16[n];
        p += __shfl_xor(p, 1);  p += __shfl_xor(p, 2);
        p += __shfl_xor(p, 4);  p += __shfl_xor(p, 8);
        p += __shfl_xor(p, 16); p += __shfl_xor(p, 32);
        a16[n] = p;
    }
    if (l == 0) {
        #pragma unroll
        for (int n = 0; n < 16; ++n) Aw[w][n] = a16[n];
    }
    __syncthreads();
    if (t < 64) {
        int f = t >> 4, n = t & 15;
        Af[f][n] = Aw[4*f][n] + Aw[4*f+1][n] + Aw[4*f+2][n] + Aw[4*f+3][n];
    }
    __syncthreads();

    // pooled + leaky relu
    float sv[16];
    {
        const float* srow = ws + WS_S + (size_t)t * 16;
        float4 v0 = *(const float4*)(srow + 0);
        float4 v1 = *(const float4*)(srow + 4);
        float4 v2 = *(const float4*)(srow + 8);
        float4 v3 = *(const float4*)(srow + 12);
        sv[0]=v0.x; sv[1]=v0.y; sv[2]=v0.z; sv[3]=v0.w;
        sv[4]=v1.x; sv[5]=v1.y; sv[6]=v1.z; sv[7]=v1.w;
        sv[8]=v2.x; sv[9]=v2.y; sv[10]=v2.z; sv[11]=v2.w;
        sv[12]=v3.x; sv[13]=v3.y; sv[14]=v3.z; sv[15]=v3.w;
    }
    float x[4];
    #pragma unroll
    for (int f = 0; f < 4; ++f) {
        float p = 0.f;
        #pragma unroll
        for (int n = 0; n < 16; ++n) p = fmaf(Af[f][n], sv[n], p);
        p *= (1.f / 16384.f);
        x[f] = (p >= 0.f) ? p : SLOPE * p;
    }

    // batch stats (mean / var over 1024 samples, per feature)
    float st[8];
    #pragma unroll
    for (int f = 0; f < 4; ++f) { st[f] = x[f]; st[4 + f] = x[f] * x[f]; }
    #pragma unroll
    for (int j = 0; j < 8; ++j) {
        float p = st[j];
        p += __shfl_xor(p, 1);  p += __shfl_xor(p, 2);
        p += __shfl_xor(p, 4);  p += __shfl_xor(p, 8);
        p += __shfl_xor(p, 16); p += __shfl_xor(p, 32);
        st[j] = p;
    }
    if (l == 0) {
        #pragma unroll
        for (int j = 0; j < 8; ++j) SWs[w][j] = st[j];
    }
    __syncthreads();
    if (t < 8) {
        float p = 0.f;
        #pragma unroll
        for (int ww = 0; ww < 16; ++ww) p += SWs[ww][t];
        FS[t] = p;
    }
    __syncthreads();
    if (t < 4) {
        float mean = FS[t] * (1.f / 1024.f);
        float var  = FS[4 + t] * (1.f / 1024.f) - mean * mean;
        float s = bn_w[t] / sqrtf(var + EPS);
        sc[t] = s;
        sh[t] = bn_b[t] - mean * s;
    }
    __syncthreads();

    float o0 = bo[0], o1 = bo[1];
    #pragma unroll
    for (int f = 0; f < 4; ++f) {
        float xh = x[f] * sc[f] + sh[f];
        o0 = fmaf(xh, Wo[f], o0);
        o1 = fmaf(xh, Wo[4 + f], o1);
    }
    float2 o = make_float2(o0, o1);
    *(float2*)(out + (size_t)t * 2) = o;
}

// ---------------- launch ----------------
extern "C" void kernel_launch(void* const* d_in, const int* in_sizes, int n_in,
                              void* d_out, int out_size, void* d_ws, size_t ws_size,
                              hipStream_t stream) {
    const float* q_input  = (const float*)d_in[0];
    const float* kv_input = (const float*)d_in[1];
    const float* Wq   = (const float*)d_in[2];
    const float* bq   = (const float*)d_in[3];
    const float* Wkv  = (const float*)d_in[4];
    const float* bkv  = (const float*)d_in[5];
    const float* bn_w = (const float*)d_in[6];
    const float* bn_b = (const float*)d_in[7];
    const float* Wo   = (const float*)d_in[8];
    const float* bo   = (const float*)d_in[9];
    float* out = (float*)d_out;
    float* ws  = (float*)d_ws;

    hipLaunchKernelGGL(prep_kernel, dim3(128), dim3(256), 0, stream, Wkv, bkv, ws);
    hipLaunchKernelGGL(gemm_qk_kernel, dim3(16, 16), dim3(256), 0, stream,
                       q_input, kv_input, Wq, Wkv, bq, bkv, ws + WS_QK);
    hipLaunchKernelGGL(attn_kernel, dim3(1024), dim3(256), 0, stream, kv_input, ws);
    hipLaunchKernelGGL(final_kernel, dim3(1), dim3(1024), 0, stream,
                       bn_w, bn_b, Wo, bo, ws, out);
}

// Round 4
// 115.231 us; speedup vs baseline: 1.5660x; 1.5660x over previous
//
#include <hip/hip_runtime.h>
#include <hip/hip_bf16.h>

#define EPS 1e-5f
#define SLOPE 0.01f

typedef __attribute__((ext_vector_type(8))) short bfrag8;   // 8 bf16 (4 VGPRs)
typedef __attribute__((ext_vector_type(4))) float f32x4;

// ---- workspace byte offsets ----
#define WS_SIM_OFF   0u          // [1024][16] f32 (zeroed by prep)
#define WS_S_OFF     65536u      // [1024][16] f32
#define WS_WVS_OFF   131072u     // [2048][16] f32, transposed [c][n]
#define WS_BVS_OFF   262144u     // [16] f32
#define WS_WBT_OFF   262400u     // tiled bf16 weights: [hb 8][s 65][col 256][40] = 10,649,600 B

// round-to-nearest-even fp32 -> bf16
__device__ __forceinline__ unsigned short f2bf(float f) {
    union { float f; unsigned int u; } x; x.f = f;
    unsigned int r = (x.u + 0x7FFFu + ((x.u >> 16) & 1u)) >> 16;
    return (unsigned short)r;
}

// ---------------- kernel 0: prep ----------------
// (a) pack Wq/Wkv-k + biases into tiled bf16 Wbt image (incl. bias K-column + pad)
// (b) WvS[c][n] = sum_d Wkv[n*128+64+d][c]  (v-projection collapsed by pooling)
// (c) zero sim   (d) bvS
#define PREP_WBT 665600          // 8*65*256*5 threads, 8 bf16 (16B) each
#define PREP_WVS (PREP_WBT + 32768)
#define PREP_SIM (PREP_WVS + 16384)
#define PREP_END (PREP_SIM + 16)

__global__ __launch_bounds__(256) void prep_kernel(
        const float* __restrict__ Wq, const float* __restrict__ bq,
        const float* __restrict__ Wkv, const float* __restrict__ bkv,
        unsigned char* __restrict__ ws) {
    int gid = blockIdx.x * 256 + threadIdx.x;
    if (gid < PREP_WBT) {
        unsigned short* wbt = (unsigned short*)(ws + WS_WBT_OFF);
        int kg = gid % 5;
        int rest = gid / 5;
        int col = rest & 255;  rest >>= 8;
        int s = rest % 65;
        int hb = rest / 65;
        int h = hb * 2 + (col >> 7);
        int j = col & 127;
        unsigned short vals[8];
        if (kg == 4) {
            #pragma unroll
            for (int e = 0; e < 8; ++e) vals[e] = 0;   // row pad (40-32)
        } else {
            const float* wrow; float bias;
            if (j < 64) { wrow = Wq  + (size_t)(h * 64 + j) * 2048;        bias = bq[h * 64 + j]; }
            else        { wrow = Wkv + (size_t)(h * 128 + (j - 64)) * 2048; bias = bkv[h * 128 + (j - 64)]; }
            int k0 = s * 32 + kg * 8;
            #pragma unroll
            for (int e = 0; e < 8; ++e) {
                int k = k0 + e;
                float v = (k < 2048) ? wrow[k] : ((k == 2048) ? bias : 0.f);
                vals[e] = f2bf(v);
            }
        }
        uint4 pk;
        pk.x = (unsigned)vals[0] | ((unsigned)vals[1] << 16);
        pk.y = (unsigned)vals[2] | ((unsigned)vals[3] << 16);
        pk.z = (unsigned)vals[4] | ((unsigned)vals[5] << 16);
        pk.w = (unsigned)vals[6] | ((unsigned)vals[7] << 16);
        *(uint4*)(wbt + (size_t)gid * 8) = pk;
    } else if (gid < PREP_WVS) {
        int g2 = gid - PREP_WBT;
        int n = g2 >> 11, c = g2 & 2047;
        const float* base = Wkv + (size_t)(n * 128 + 64) * 2048 + c;
        float s = 0.f;
        #pragma unroll 8
        for (int d = 0; d < 64; ++d) s += base[(size_t)d * 2048];
        ((float*)(ws + WS_WVS_OFF))[c * 16 + n] = s;
    } else if (gid < PREP_SIM) {
        ((float*)(ws + WS_SIM_OFF))[gid - PREP_WVS] = 0.f;
    } else if (gid < PREP_END) {
        int n = gid - PREP_SIM;
        float b = 0.f;
        #pragma unroll
        for (int d = 0; d < 64; ++d) b += bkv[n * 128 + 64 + d];
        ((float*)(ws + WS_BVS_OFF))[n] = b;
    }
}

// ---------------- kernel 1: fused q/k projection + per-head dot (MFMA) ----------------
// grid (mb=64, hb=8), 256 threads = 4 waves; wave w: wc=(w&1) d-half, wh=(w>>1) head.
// Each wave accumulates the FULL K=2048(+bias) projection for q and k into fp32
// accumulators, THEN pairs Cq*Ck elementwise and reduces over d (algebraically exact;
// the previous kc-split dropped bilinear cross terms).
__global__ __launch_bounds__(256) void gemm_sim_kernel(
        const float* __restrict__ qin, const float* __restrict__ kvin,
        unsigned char* __restrict__ ws) {
    __shared__ alignas(16) unsigned short Aq[16][40];
    __shared__ alignas(16) unsigned short Akv[16][40];
    __shared__ alignas(16) unsigned short Bt[256][40];

    int t = threadIdx.x;
    int w = t >> 6, l = t & 63;
    int mb = blockIdx.x, hb = blockIdx.y;
    int m0 = mb * 16;
    int wc = w & 1, wh = w >> 1;

    const unsigned char* wbt = ws + WS_WBT_OFF;
    float* sim = (float*)(ws + WS_SIM_OFF);

    f32x4 accq[2], acck[2];
    accq[0] = (f32x4)0.f; accq[1] = (f32x4)0.f;
    acck[0] = (f32x4)0.f; acck[1] = (f32x4)0.f;

    // A staging: threads 0-127 -> Aq, 128-255 -> Akv ; 1 float4 each per s-step
    int ish = t >> 7;
    int tt = t & 127;
    int arow = tt >> 3;          // 0..15
    int ako  = (tt & 7) * 4;     // 0,4,...,28
    const float* a_src = (ish ? kvin : qin) + (size_t)(m0 + arow) * 2048 + ako;
    unsigned short* a_dst = (ish ? &Akv[0][0] : &Aq[0][0]) + arow * 40 + ako;

    int lrow = l & 15, lko = (l >> 4) * 8;
    int bqb = wh * 128 + wc * 32;

    for (int s = 0; s < 65; ++s) {
        int k0 = s * 32;
        __syncthreads();             // protect LDS from previous iter's readers
        // ---- A panels: fp32 -> bf16 reg-staged (bias column synthesized at s=64) ----
        float4 a4;
        if (k0 < 2048) {
            a4 = *(const float4*)(a_src + k0);
        } else {
            float one = (ako == 0) ? 1.f : 0.f;   // element k=2048 is the bias-1 column
            a4 = make_float4(one, 0.f, 0.f, 0.f);
        }
        ushort4 ap;
        ap.x = f2bf(a4.x); ap.y = f2bf(a4.y); ap.z = f2bf(a4.z); ap.w = f2bf(a4.w);
        *(ushort4*)a_dst = ap;
        // ---- B panel: tiled bf16 image -> LDS via global_load_lds (width 16) ----
        const unsigned char* wsrc = wbt + (size_t)(hb * 65 + s) * 20480;
        unsigned char* bdst = (unsigned char*)&Bt[0][0];
        for (int i = w; i < 20; i += 4) {
            auto gsrc = (const __attribute__((address_space(1))) unsigned int*)(const void*)(wsrc + i * 1024 + l * 16);
            auto ldst = (__attribute__((address_space(3))) unsigned int*)(void*)(bdst + i * 1024);
            __builtin_amdgcn_global_load_lds(gsrc, ldst, 16, 0, 0);
        }
        __syncthreads();
        // ---- fragments + MFMA (accumulate full K before pairing) ----
        bfrag8 fa_q = *(const bfrag8*)&Aq[lrow][lko];
        bfrag8 fa_k = *(const bfrag8*)&Akv[lrow][lko];
        #pragma unroll
        for (int ni = 0; ni < 2; ++ni) {
            bfrag8 fbq = *(const bfrag8*)&Bt[bqb + 16 * ni + lrow][lko];
            bfrag8 fbk = *(const bfrag8*)&Bt[bqb + 64 + 16 * ni + lrow][lko];
            accq[ni] = __builtin_amdgcn_mfma_f32_16x16x32_bf16(fa_q, fbq, accq[ni], 0, 0, 0);
            acck[ni] = __builtin_amdgcn_mfma_f32_16x16x32_bf16(fa_k, fbk, acck[ni], 0, 0, 0);
        }
    }
    // ---- epilogue: pair Cq*Ck elementwise (same lane = same row,d), reduce over d ----
    int head = hb * 2 + wh;
    f32x4 p = accq[0] * acck[0] + accq[1] * acck[1];
    #pragma unroll
    for (int r = 0; r < 4; ++r) {
        float v = p[r];
        v += __shfl_xor(v, 1); v += __shfl_xor(v, 2);
        v += __shfl_xor(v, 4); v += __shfl_xor(v, 8);
        if ((l & 15) == 0) {
            int row = m0 + (l >> 4) * 4 + r;
            atomicAdd(&sim[row * 16 + head], v);   // 2 contributions per cell (wc halves)
        }
    }
}

// ---------------- kernel 2: S[b][n] = kv_input[b]·WvS[:,n] + bvS[n] (fp32) ----------------
__global__ __launch_bounds__(256) void s_kernel(
        const float* __restrict__ kvin, unsigned char* __restrict__ ws) {
    int b = blockIdx.x, t = threadIdx.x;
    int w = t >> 6, l = t & 63;
    __shared__ float SW[4][16];
    int n = t & 15, g = t >> 4;             // g 0..15
    const float* kvrow = kvin + (size_t)b * 2048;
    const float* wv = (const float*)(ws + WS_WVS_OFF);
    float p = 0.f;
    #pragma unroll 4
    for (int tt = 0; tt < 128; ++tt) {
        int c = g + (tt << 4);
        p = fmaf(kvrow[c], wv[c * 16 + n], p);
    }
    p += __shfl_xor(p, 16);
    p += __shfl_xor(p, 32);
    if (l < 16) SW[w][n] = p;
    __syncthreads();
    if (t < 16) {
        float sv = SW[0][t] + SW[1][t] + SW[2][t] + SW[3][t]
                 + ((const float*)(ws + WS_BVS_OFF))[t];
        ((float*)(ws + WS_S_OFF))[b * 16 + t] = sv;
    }
}

// ---------------- kernel 3: softmax, A-reduce, pooled, leaky, batchnorm, output ----------------
__global__ __launch_bounds__(1024) void final_kernel(
        const float* __restrict__ bn_w, const float* __restrict__ bn_b,
        const float* __restrict__ Wo, const float* __restrict__ bo,
        const unsigned char* __restrict__ ws, float* __restrict__ out) {
    int t = threadIdx.x;
    int w = t >> 6;
    int l = t & 63;
    __shared__ float Aw[16][16];
    __shared__ float Af[4][16];
    __shared__ float SWs[16][8];
    __shared__ float FS[8];
    __shared__ float sc[4], sh[4];

    // softmax over heads for sample t (in-register)
    float a16[16];
    {
        const float* srow = (const float*)(ws + WS_SIM_OFF) + (size_t)t * 16;
        float4 v0 = *(const float4*)(srow + 0);
        float4 v1 = *(const float4*)(srow + 4);
        float4 v2 = *(const float4*)(srow + 8);
        float4 v3 = *(const float4*)(srow + 12);
        a16[0]=v0.x; a16[1]=v0.y; a16[2]=v0.z; a16[3]=v0.w;
        a16[4]=v1.x; a16[5]=v1.y; a16[6]=v1.z; a16[7]=v1.w;
        a16[8]=v2.x; a16[9]=v2.y; a16[10]=v2.z; a16[11]=v2.w;
        a16[12]=v3.x; a16[13]=v3.y; a16[14]=v3.z; a16[15]=v3.w;
        float m = a16[0];
        #pragma unroll
        for (int n = 1; n < 16; ++n) m = fmaxf(m, a16[n]);
        float den = 0.f;
        #pragma unroll
        for (int n = 0; n < 16; ++n) { a16[n] = expf(a16[n] - m); den += a16[n]; }
        float inv = 1.f / den;
        #pragma unroll
        for (int n = 0; n < 16; ++n) a16[n] *= inv;
    }
    // A[f,n] = sum of att rows in chunk f (chunk = 4 consecutive waves)
    #pragma unroll
    for (int n = 0; n < 16; ++n) {
        float p = a16[n];
        p += __shfl_xor(p, 1);  p += __shfl_xor(p, 2);
        p += __shfl_xor(p, 4);  p += __shfl_xor(p, 8);
        p += __shfl_xor(p, 16); p += __shfl_xor(p, 32);
        a16[n] = p;
    }
    if (l == 0) {
        #pragma unroll
        for (int n = 0; n < 16; ++n) Aw[w][n] = a16[n];
    }
    __syncthreads();
    if (t < 64) {
        int f = t >> 4, n = t & 15;
        Af[f][n] = Aw[4*f][n] + Aw[4*f+1][n] + Aw[4*f+2][n] + Aw[4*f+3][n];
    }
    __syncthreads();

    // pooled + leaky relu
    float sv[16];
    {
        const float* srow = (const float*)(ws + WS_S_OFF) + (size_t)t * 16;
        float4 v0 = *(const float4*)(srow + 0);
        float4 v1 = *(const float4*)(srow + 4);
        float4 v2 = *(const float4*)(srow + 8);
        float4 v3 = *(const float4*)(srow + 12);
        sv[0]=v0.x; sv[1]=v0.y; sv[2]=v0.z; sv[3]=v0.w;
        sv[4]=v1.x; sv[5]=v1.y; sv[6]=v1.z; sv[7]=v1.w;
        sv[8]=v2.x; sv[9]=v2.y; sv[10]=v2.z; sv[11]=v2.w;
        sv[12]=v3.x; sv[13]=v3.y; sv[14]=v3.z; sv[15]=v3.w;
    }
    float x[4];
    #pragma unroll
    for (int f = 0; f < 4; ++f) {
        float p = 0.f;
        #pragma unroll
        for (int n = 0; n < 16; ++n) p = fmaf(Af[f][n], sv[n], p);
        p *= (1.f / 16384.f);
        x[f] = (p >= 0.f) ? p : SLOPE * p;
    }

    // batch stats
    float st[8];
    #pragma unroll
    for (int f = 0; f < 4; ++f) { st[f] = x[f]; st[4 + f] = x[f] * x[f]; }
    #pragma unroll
    for (int j = 0; j < 8; ++j) {
        float p = st[j];
        p += __shfl_xor(p, 1);  p += __shfl_xor(p, 2);
        p += __shfl_xor(p, 4);  p += __shfl_xor(p, 8);
        p += __shfl_xor(p, 16); p += __shfl_xor(p, 32);
        st[j] = p;
    }
    if (l == 0) {
        #pragma unroll
        for (int j = 0; j < 8; ++j) SWs[w][j] = st[j];
    }
    __syncthreads();
    if (t < 8) {
        float p = 0.f;
        #pragma unroll
        for (int ww = 0; ww < 16; ++ww) p += SWs[ww][t];
        FS[t] = p;
    }
    __syncthreads();
    if (t < 4) {
        float mean = FS[t] * (1.f / 1024.f);
        float var  = FS[4 + t] * (1.f / 1024.f) - mean * mean;
        float s = bn_w[t] / sqrtf(var + EPS);
        sc[t] = s;
        sh[t] = bn_b[t] - mean * s;
    }
    __syncthreads();

    float o0 = bo[0], o1 = bo[1];
    #pragma unroll
    for (int f = 0; f < 4; ++f) {
        float xh = x[f] * sc[f] + sh[f];
        o0 = fmaf(xh, Wo[f], o0);
        o1 = fmaf(xh, Wo[4 + f], o1);
    }
    *(float2*)(out + (size_t)t * 2) = make_float2(o0, o1);
}

// ---------------- launch ----------------
extern "C" void kernel_launch(void* const* d_in, const int* in_sizes, int n_in,
                              void* d_out, int out_size, void* d_ws, size_t ws_size,
                              hipStream_t stream) {
    const float* q_input  = (const float*)d_in[0];
    const float* kv_input = (const float*)d_in[1];
    const float* Wq   = (const float*)d_in[2];
    const float* bq   = (const float*)d_in[3];
    const float* Wkv  = (const float*)d_in[4];
    const float* bkv  = (const float*)d_in[5];
    const float* bn_w = (const float*)d_in[6];
    const float* bn_b = (const float*)d_in[7];
    const float* Wo   = (const float*)d_in[8];
    const float* bo   = (const float*)d_in[9];
    float* out = (float*)d_out;
    unsigned char* ws = (unsigned char*)d_ws;

    hipLaunchKernelGGL(prep_kernel, dim3((PREP_END + 255) / 256), dim3(256), 0, stream,
                       Wq, bq, Wkv, bkv, ws);
    hipLaunchKernelGGL(gemm_sim_kernel, dim3(64, 8), dim3(256), 0, stream,
                       q_input, kv_input, ws);
    hipLaunchKernelGGL(s_kernel, dim3(1024), dim3(256), 0, stream, kv_input, ws);
    hipLaunchKernelGGL(final_kernel, dim3(1), dim3(1024), 0, stream,
                       bn_w, bn_b, Wo, bo, ws, out);
}

// Round 5
// 82.587 us; speedup vs baseline: 2.1850x; 1.3953x over previous
//
#include <hip/hip_runtime.h>
#include <hip/hip_bf16.h>

#define EPS 1e-5f
#define SLOPE 0.01f

typedef __attribute__((ext_vector_type(8))) short bfrag8;   // 8 bf16 (4 VGPRs)
typedef __attribute__((ext_vector_type(4))) float f32x4;

// ---- workspace byte offsets ----
#define WS_SIM_OFF   0u          // [1024][16] f32 (zeroed by prep)
#define WS_S_OFF     65536u      // [1024][16] f32
#define WS_WVS_OFF   131072u     // [2048][16] f32, transposed [c][n]
#define WS_BVS_OFF   262144u     // [16] f32
#define WS_WBT_OFF   262400u     // bf16 image: [hb 8][s 64][col 256][40] = 10,485,760 B

// round-to-nearest-even fp32 -> bf16
__device__ __forceinline__ unsigned short f2bf(float f) {
    union { float f; unsigned int u; } x; x.f = f;
    unsigned int r = (x.u + 0x7FFFu + ((x.u >> 16) & 1u)) >> 16;
    return (unsigned short)r;
}

// ---------------- kernel 0: prep ----------------
// (a) pack Wq/Wkv-k into tiled bf16 image (K=2048, no bias column — bias applied fp32 in gemm)
// (b) WvS[c][n] = sum_d Wkv[n*128+64+d][c]   (c) zero sim   (d) bvS
#define PREP_WBT (8*64*256*5)    // 655360 threads, 8 bf16 (16B) each
#define PREP_WVS (PREP_WBT + 32768)
#define PREP_SIM (PREP_WVS + 16384)
#define PREP_END (PREP_SIM + 16)

__global__ __launch_bounds__(256) void prep_kernel(
        const float* __restrict__ Wq, const float* __restrict__ bq,
        const float* __restrict__ Wkv, const float* __restrict__ bkv,
        unsigned char* __restrict__ ws) {
    int gid = blockIdx.x * 256 + threadIdx.x;
    if (gid < PREP_WBT) {
        unsigned short* wbt = (unsigned short*)(ws + WS_WBT_OFF);
        int kg = gid % 5;
        int rest = gid / 5;
        int col = rest & 255;  rest >>= 8;
        int s = rest & 63;
        int hb = rest >> 6;
        int hpar = col >> 7;              // head within pair
        int j = col & 127;                // j<64: q col j ; j>=64: k col j-64
        int hsel = hb * 2 + hpar;
        unsigned short vals[8];
        if (kg == 4) {
            #pragma unroll
            for (int e = 0; e < 8; ++e) vals[e] = 0;   // row pad (40-32)
        } else {
            const float* wrow;
            if (j < 64) wrow = Wq  + (size_t)(hsel * 64 + j) * 2048;
            else        wrow = Wkv + (size_t)(hsel * 128 + (j - 64)) * 2048;
            int k0 = s * 32 + kg * 8;
            #pragma unroll
            for (int e = 0; e < 8; ++e) vals[e] = f2bf(wrow[k0 + e]);
        }
        uint4 pk;
        pk.x = (unsigned)vals[0] | ((unsigned)vals[1] << 16);
        pk.y = (unsigned)vals[2] | ((unsigned)vals[3] << 16);
        pk.z = (unsigned)vals[4] | ((unsigned)vals[5] << 16);
        pk.w = (unsigned)vals[6] | ((unsigned)vals[7] << 16);
        *(uint4*)(wbt + (size_t)gid * 8) = pk;
    } else if (gid < PREP_WVS) {
        int g2 = gid - PREP_WBT;
        int n = g2 >> 11, c = g2 & 2047;
        const float* base = Wkv + (size_t)(n * 128 + 64) * 2048 + c;
        float s = 0.f;
        #pragma unroll 8
        for (int d = 0; d < 64; ++d) s += base[(size_t)d * 2048];
        ((float*)(ws + WS_WVS_OFF))[c * 16 + n] = s;
    } else if (gid < PREP_SIM) {
        ((float*)(ws + WS_SIM_OFF))[gid - PREP_WVS] = 0.f;
    } else if (gid < PREP_END) {
        int n = gid - PREP_SIM;
        float b = 0.f;
        #pragma unroll
        for (int d = 0; d < 64; ++d) b += bkv[n * 128 + 64 + d];
        ((float*)(ws + WS_BVS_OFF))[n] = b;
    }
}

// ---------------- kernel 1: fused q/k projection + per-head dot (MFMA, 2-phase) ----------------
// grid (x=hb 8, y=mb 32) -> dispatch id % 8 == hb: each XCD pins one weight panel in L2.
// 512 threads = 8 waves: w = hh*4 + qk*2 + dw.
// Wave computes the full-K 32x32 projection tile (q or k) for head hb*2+hh, d-half dw.
// Pairing Cq*Ck happens ONCE in the epilogue (full-K accumulated first — bilinear-exact).
__global__ __launch_bounds__(512) void gemm_sim_kernel(
        const float* __restrict__ qin, const float* __restrict__ kvin,
        const float* __restrict__ bq, const float* __restrict__ bkv,
        unsigned char* __restrict__ ws) {
    __shared__ unsigned short Bt[2][2][256][40];   // 80 KB: [buf][ksub][col][40]
    __shared__ unsigned short Aq[2][2][32][40];    // 10 KB
    __shared__ unsigned short Akv[2][2][32][40];   // 10 KB
    __shared__ float Cqs[2][2][32][32];            // 16 KB pairing buffer [hh][dw][row][d]

    int t = threadIdx.x;
    int w = t >> 6, l = t & 63;
    int hb = blockIdx.x, mb = blockIdx.y;
    int m0 = mb * 32;
    int hh = w >> 2, qk = (w >> 1) & 1, dw = w & 1;
    int lrow = l & 15, lko = (l >> 4) * 8;
    int cb = hh * 128 + qk * 64 + dw * 32;         // wave's B col base
    int h = hb * 2 + hh;

    const unsigned char* wbt = ws + WS_WBT_OFF;
    float* sim = (float*)(ws + WS_SIM_OFF);

    f32x4 acc[2][2];
    acc[0][0] = (f32x4)0.f; acc[0][1] = (f32x4)0.f;
    acc[1][0] = (f32x4)0.f; acc[1][1] = (f32x4)0.f;

    // A staging map: thread t -> row t>>4, float4 piece t&15
    int arow = t >> 4, akp = t & 15;
    const float* aq_src = qin  + (size_t)(m0 + arow) * 2048 + akp * 4;
    const float* ak_src = kvin + (size_t)(m0 + arow) * 2048 + akp * 4;
    int adst = (akp >> 3) * 1280 + arow * 40 + (akp & 7) * 4;   // elem offset in [2][32][40]

    // exact fp32 bias for this wave's columns (C/D col = lane&15, m89-verified)
    float biasv[2];
    #pragma unroll
    for (int ni = 0; ni < 2; ++ni) {
        int d = dw * 32 + 16 * ni + lrow;
        biasv[ni] = qk ? bkv[h * 128 + d] : bq[h * 64 + d];
    }

    // ---- prologue: stage iter 0 ----
    float4 rq = *(const float4*)(aq_src);
    float4 rk = *(const float4*)(ak_src);
    {
        const unsigned char* src = wbt + (size_t)(hb * 64) * 20480;
        unsigned char* dst = (unsigned char*)&Bt[0][0][0][0];
        #pragma unroll
        for (int j = 0; j < 5; ++j) {
            int lin = j * 512 + t;
            __builtin_amdgcn_global_load_lds(
                (const __attribute__((address_space(1))) unsigned int*)(const void*)(src + lin * 16),
                (__attribute__((address_space(3))) unsigned int*)(void*)(dst + lin * 16), 16, 0, 0);
        }
    }
    {
        ushort4 pq, pk;
        pq.x = f2bf(rq.x); pq.y = f2bf(rq.y); pq.z = f2bf(rq.z); pq.w = f2bf(rq.w);
        pk.x = f2bf(rk.x); pk.y = f2bf(rk.y); pk.z = f2bf(rk.z); pk.w = f2bf(rk.w);
        *(ushort4*)(&Aq[0][0][0][0]  + adst) = pq;
        *(ushort4*)(&Akv[0][0][0][0] + adst) = pk;
    }
    __syncthreads();

    // ---- main loop: 32 iters of BK=64, one barrier each, stage-before-compute ----
    int cur = 0;
    for (int i = 0; i < 32; ++i) {
        float4 rq2, rk2;
        if (i < 31) {
            rq2 = *(const float4*)(aq_src + (i + 1) * 64);
            rk2 = *(const float4*)(ak_src + (i + 1) * 64);
            const unsigned char* src = wbt + (size_t)(hb * 64 + 2 * (i + 1)) * 20480;
            unsigned char* dst = (unsigned char*)&Bt[cur ^ 1][0][0][0];
            #pragma unroll
            for (int j = 0; j < 5; ++j) {
                int lin = j * 512 + t;
                __builtin_amdgcn_global_load_lds(
                    (const __attribute__((address_space(1))) unsigned int*)(const void*)(src + lin * 16),
                    (__attribute__((address_space(3))) unsigned int*)(void*)(dst + lin * 16), 16, 0, 0);
            }
        }
        // compute current buffer
        {
            const unsigned short* Ab = qk ? &Akv[cur][0][0][0] : &Aq[cur][0][0][0];
            const unsigned short* Bb = &Bt[cur][0][0][0];
            #pragma unroll
            for (int ks = 0; ks < 2; ++ks) {
                bfrag8 fa0 = *(const bfrag8*)(Ab + ks * 1280 + lrow * 40 + lko);
                bfrag8 fa1 = *(const bfrag8*)(Ab + ks * 1280 + (16 + lrow) * 40 + lko);
                bfrag8 fb0 = *(const bfrag8*)(Bb + ks * 10240 + (cb + lrow) * 40 + lko);
                bfrag8 fb1 = *(const bfrag8*)(Bb + ks * 10240 + (cb + 16 + lrow) * 40 + lko);
                acc[0][0] = __builtin_amdgcn_mfma_f32_16x16x32_bf16(fa0, fb0, acc[0][0], 0, 0, 0);
                acc[0][1] = __builtin_amdgcn_mfma_f32_16x16x32_bf16(fa0, fb1, acc[0][1], 0, 0, 0);
                acc[1][0] = __builtin_amdgcn_mfma_f32_16x16x32_bf16(fa1, fb0, acc[1][0], 0, 0, 0);
                acc[1][1] = __builtin_amdgcn_mfma_f32_16x16x32_bf16(fa1, fb1, acc[1][1], 0, 0, 0);
            }
        }
        if (i < 31) {   // write A(i+1) into next buffer (readers of it passed the last barrier)
            ushort4 pq, pk;
            pq.x = f2bf(rq2.x); pq.y = f2bf(rq2.y); pq.z = f2bf(rq2.z); pq.w = f2bf(rq2.w);
            pk.x = f2bf(rk2.x); pk.y = f2bf(rk2.y); pk.z = f2bf(rk2.z); pk.w = f2bf(rk2.w);
            *(ushort4*)(&Aq[cur ^ 1][0][0][0]  + adst) = pq;
            *(ushort4*)(&Akv[cur ^ 1][0][0][0] + adst) = pk;
        }
        __syncthreads();
        cur ^= 1;
    }

    // ---- epilogue: + bias (fp32 exact), pair Cq*Ck, reduce over d, atomicAdd sim ----
    #pragma unroll
    for (int rm = 0; rm < 2; ++rm)
        #pragma unroll
        for (int ni = 0; ni < 2; ++ni)
            #pragma unroll
            for (int r = 0; r < 4; ++r)
                acc[rm][ni][r] += biasv[ni];

    if (!qk) {
        #pragma unroll
        for (int rm = 0; rm < 2; ++rm)
            #pragma unroll
            for (int ni = 0; ni < 2; ++ni)
                #pragma unroll
                for (int r = 0; r < 4; ++r) {
                    int row = rm * 16 + (l >> 4) * 4 + r;
                    Cqs[hh][dw][row][ni * 16 + lrow] = acc[rm][ni][r];
                }
    }
    __syncthreads();
    if (qk) {
        #pragma unroll
        for (int rm = 0; rm < 2; ++rm) {
            float p[4];
            #pragma unroll
            for (int r = 0; r < 4; ++r) {
                int row = rm * 16 + (l >> 4) * 4 + r;
                p[r] = Cqs[hh][dw][row][lrow]      * acc[rm][0][r]
                     + Cqs[hh][dw][row][16 + lrow] * acc[rm][1][r];
            }
            #pragma unroll
            for (int r = 0; r < 4; ++r) {
                float v = p[r];
                v += __shfl_xor(v, 1); v += __shfl_xor(v, 2);
                v += __shfl_xor(v, 4); v += __shfl_xor(v, 8);
                if ((l & 15) == 0) {
                    int row = m0 + rm * 16 + (l >> 4) * 4 + r;
                    atomicAdd(&sim[row * 16 + h], v);   // 2 adds/cell (dw halves)
                }
            }
        }
    }
}

// ---------------- kernel 2: S[b][n] = kv_input[b]·WvS[:,n] + bvS[n] (fp32) ----------------
__global__ __launch_bounds__(256) void s_kernel(
        const float* __restrict__ kvin, unsigned char* __restrict__ ws) {
    int b = blockIdx.x, t = threadIdx.x;
    int w = t >> 6, l = t & 63;
    __shared__ float SW[4][16];
    int n = t & 15, g = t >> 4;
    const float* kvrow = kvin + (size_t)b * 2048;
    const float* wv = (const float*)(ws + WS_WVS_OFF);
    float p = 0.f;
    #pragma unroll 4
    for (int tt = 0; tt < 128; ++tt) {
        int c = g + (tt << 4);
        p = fmaf(kvrow[c], wv[c * 16 + n], p);
    }
    p += __shfl_xor(p, 16);
    p += __shfl_xor(p, 32);
    if (l < 16) SW[w][n] = p;
    __syncthreads();
    if (t < 16) {
        float sv = SW[0][t] + SW[1][t] + SW[2][t] + SW[3][t]
                 + ((const float*)(ws + WS_BVS_OFF))[t];
        ((float*)(ws + WS_S_OFF))[b * 16 + t] = sv;
    }
}

// ---------------- kernel 3: softmax, A-reduce, pooled, leaky, batchnorm, output ----------------
__global__ __launch_bounds__(1024) void final_kernel(
        const float* __restrict__ bn_w, const float* __restrict__ bn_b,
        const float* __restrict__ Wo, const float* __restrict__ bo,
        const unsigned char* __restrict__ ws, float* __restrict__ out) {
    int t = threadIdx.x;
    int w = t >> 6;
    int l = t & 63;
    __shared__ float Aw[16][16];
    __shared__ float Af[4][16];
    __shared__ float SWs[16][8];
    __shared__ float FS[8];
    __shared__ float sc[4], sh[4];

    float a16[16];
    {
        const float* srow = (const float*)(ws + WS_SIM_OFF) + (size_t)t * 16;
        float4 v0 = *(const float4*)(srow + 0);
        float4 v1 = *(const float4*)(srow + 4);
        float4 v2 = *(const float4*)(srow + 8);
        float4 v3 = *(const float4*)(srow + 12);
        a16[0]=v0.x; a16[1]=v0.y; a16[2]=v0.z; a16[3]=v0.w;
        a16[4]=v1.x; a16[5]=v1.y; a16[6]=v1.z; a16[7]=v1.w;
        a16[8]=v2.x; a16[9]=v2.y; a16[10]=v2.z; a16[11]=v2.w;
        a16[12]=v3.x; a16[13]=v3.y; a16[14]=v3.z; a16[15]=v3.w;
        float m = a16[0];
        #pragma unroll
        for (int n = 1; n < 16; ++n) m = fmaxf(m, a16[n]);
        float den = 0.f;
        #pragma unroll
        for (int n = 0; n < 16; ++n) { a16[n] = expf(a16[n] - m); den += a16[n]; }
        float inv = 1.f / den;
        #pragma unroll
        for (int n = 0; n < 16; ++n) a16[n] *= inv;
    }
    #pragma unroll
    for (int n = 0; n < 16; ++n) {
        float p = a16[n];
        p += __shfl_xor(p, 1);  p += __shfl_xor(p, 2);
        p += __shfl_xor(p, 4);  p += __shfl_xor(p, 8);
        p += __shfl_xor(p, 16); p += __shfl_xor(p, 32);
        a16[n] = p;
    }
    if (l == 0) {
        #pragma unroll
        for (int n = 0; n < 16; ++n) Aw[w][n] = a16[n];
    }
    __syncthreads();
    if (t < 64) {
        int f = t >> 4, n = t & 15;
        Af[f][n] = Aw[4*f][n] + Aw[4*f+1][n] + Aw[4*f+2][n] + Aw[4*f+3][n];
    }
    __syncthreads();

    float sv[16];
    {
        const float* srow = (const float*)(ws + WS_S_OFF) + (size_t)t * 16;
        float4 v0 = *(const float4*)(srow + 0);
        float4 v1 = *(const float4*)(srow + 4);
        float4 v2 = *(const float4*)(srow + 8);
        float4 v3 = *(const float4*)(srow + 12);
        sv[0]=v0.x; sv[1]=v0.y; sv[2]=v0.z; sv[3]=v0.w;
        sv[4]=v1.x; sv[5]=v1.y; sv[6]=v1.z; sv[7]=v1.w;
        sv[8]=v2.x; sv[9]=v2.y; sv[10]=v2.z; sv[11]=v2.w;
        sv[12]=v3.x; sv[13]=v3.y; sv[14]=v3.z; sv[15]=v3.w;
    }
    float x[4];
    #pragma unroll
    for (int f = 0; f < 4; ++f) {
        float p = 0.f;
        #pragma unroll
        for (int n = 0; n < 16; ++n) p = fmaf(Af[f][n], sv[n], p);
        p *= (1.f / 16384.f);
        x[f] = (p >= 0.f) ? p : SLOPE * p;
    }

    float st[8];
    #pragma unroll
    for (int f = 0; f < 4; ++f) { st[f] = x[f]; st[4 + f] = x[f] * x[f]; }
    #pragma unroll
    for (int j = 0; j < 8; ++j) {
        float p = st[j];
        p += __shfl_xor(p, 1);  p += __shfl_xor(p, 2);
        p += __shfl_xor(p, 4);  p += __shfl_xor(p, 8);
        p += __shfl_xor(p, 16); p += __shfl_xor(p, 32);
        st[j] = p;
    }
    if (l == 0) {
        #pragma unroll
        for (int j = 0; j < 8; ++j) SWs[w][j] = st[j];
    }
    __syncthreads();
    if (t < 8) {
        float p = 0.f;
        #pragma unroll
        for (int ww = 0; ww < 16; ++ww) p += SWs[ww][t];
        FS[t] = p;
    }
    __syncthreads();
    if (t < 4) {
        float mean = FS[t] * (1.f / 1024.f);
        float var  = FS[4 + t] * (1.f / 1024.f) - mean * mean;
        float s = bn_w[t] / sqrtf(var + EPS);
        sc[t] = s;
        sh[t] = bn_b[t] - mean * s;
    }
    __syncthreads();

    float o0 = bo[0], o1 = bo[1];
    #pragma unroll
    for (int f = 0; f < 4; ++f) {
        float xh = x[f] * sc[f] + sh[f];
        o0 = fmaf(xh, Wo[f], o0);
        o1 = fmaf(xh, Wo[4 + f], o1);
    }
    *(float2*)(out + (size_t)t * 2) = make_float2(o0, o1);
}

// ---------------- launch ----------------
extern "C" void kernel_launch(void* const* d_in, const int* in_sizes, int n_in,
                              void* d_out, int out_size, void* d_ws, size_t ws_size,
                              hipStream_t stream) {
    const float* q_input  = (const float*)d_in[0];
    const float* kv_input = (const float*)d_in[1];
    const float* Wq   = (const float*)d_in[2];
    const float* bq   = (const float*)d_in[3];
    const float* Wkv  = (const float*)d_in[4];
    const float* bkv  = (const float*)d_in[5];
    const float* bn_w = (const float*)d_in[6];
    const float* bn_b = (const float*)d_in[7];
    const float* Wo   = (const float*)d_in[8];
    const float* bo   = (const float*)d_in[9];
    float* out = (float*)d_out;
    unsigned char* ws = (unsigned char*)d_ws;

    hipLaunchKernelGGL(prep_kernel, dim3((PREP_END + 255) / 256), dim3(256), 0, stream,
                       Wq, bq, Wkv, bkv, ws);
    hipLaunchKernelGGL(gemm_sim_kernel, dim3(8, 32), dim3(512), 0, stream,
                       q_input, kv_input, bq, bkv, ws);
    hipLaunchKernelGGL(s_kernel, dim3(1024), dim3(256), 0, stream, kv_input, ws);
    hipLaunchKernelGGL(final_kernel, dim3(1), dim3(1024), 0, stream,
                       bn_w, bn_b, Wo, bo, ws, out);
}

// Round 6
// 67.626 us; speedup vs baseline: 2.6684x; 1.2212x over previous
//
#include <hip/hip_runtime.h>
#include <hip/hip_bf16.h>

#define EPS 1e-5f
#define SLOPE 0.01f

typedef __attribute__((ext_vector_type(8))) short bfrag8;   // 8 bf16 (4 VGPRs)
typedef __attribute__((ext_vector_type(4))) float f32x4;

#define AS1 __attribute__((address_space(1)))
#define AS3 __attribute__((address_space(3)))

// ---- workspace byte offsets ----
#define WS_SIM_OFF   0u          // [1024][16] f32 (zeroed by prep)
#define WS_S_OFF     65536u      // [1024][16] f32
#define WS_WVS_OFF   131072u     // [2048][16] f32, transposed [c][n]
#define WS_BVS_OFF   262144u     // [16] f32
#define WS_WBT_OFF   262208u     // bf16 B image: [h 16][it 32][ks 2][col 128][kk 32] = 8,388,608 B

// round-to-nearest-even fp32 -> bf16
__device__ __forceinline__ unsigned short f2bf(float f) {
    union { float f; unsigned int u; } x; x.f = f;
    unsigned int r = (x.u + 0x7FFFu + ((x.u >> 16) & 1u)) >> 16;
    return (unsigned short)r;
}
__device__ __forceinline__ uint4 pack8(const float4& a, const float4& b) {
    uint4 r;
    r.x = (unsigned)f2bf(a.x) | ((unsigned)f2bf(a.y) << 16);
    r.y = (unsigned)f2bf(a.z) | ((unsigned)f2bf(a.w) << 16);
    r.z = (unsigned)f2bf(b.x) | ((unsigned)f2bf(b.y) << 16);
    r.w = (unsigned)f2bf(b.z) | ((unsigned)f2bf(b.w) << 16);
    return r;
}

// ---------------- kernel 0: prep ----------------
// (a) B image: col<64 -> Wq[h*64+col], col>=64 -> Wkv[h*128+(col-64)] (k-part), bf16
// (b) WvS[c][n] = sum_d Wkv[n*128+64+d][c]   (c) zero sim   (d) bvS
#define PREP_B   524288                 // 16*32*2*128*4 granules of 8 elems (16 B each)
#define PREP_WVSE (PREP_B + 32768)
#define PREP_SIME (PREP_WVSE + 16384)
#define PREP_END  (PREP_SIME + 16)

__global__ __launch_bounds__(256) void prep_kernel(
        const float* __restrict__ Wq, const float* __restrict__ bq,
        const float* __restrict__ Wkv, const float* __restrict__ bkv,
        unsigned char* __restrict__ ws) {
    int gid = blockIdx.x * 256 + threadIdx.x;
    if (gid < PREP_B) {
        unsigned short* wbt = (unsigned short*)(ws + WS_WBT_OFF);
        int kkg = gid & 3;
        int col = (gid >> 2) & 127;
        int ks  = (gid >> 9) & 1;
        int it  = (gid >> 10) & 31;
        int h   = gid >> 15;
        const float* wrow = (col < 64) ? (Wq  + (size_t)(h * 64 + col) * 2048)
                                       : (Wkv + (size_t)(h * 128 + (col - 64)) * 2048);
        int k0 = it * 64 + ks * 32 + kkg * 8;
        float4 v0 = *(const float4*)(wrow + k0);
        float4 v1 = *(const float4*)(wrow + k0 + 4);
        *(uint4*)(wbt + (size_t)gid * 8) = pack8(v0, v1);
    } else if (gid < PREP_WVSE) {
        int g2 = gid - PREP_B;
        int n = g2 >> 11, c = g2 & 2047;
        const float* base = Wkv + (size_t)(n * 128 + 64) * 2048 + c;
        float s = 0.f;
        #pragma unroll 8
        for (int d = 0; d < 64; ++d) s += base[(size_t)d * 2048];
        ((float*)(ws + WS_WVS_OFF))[c * 16 + n] = s;
    } else if (gid < PREP_SIME) {
        ((float*)(ws + WS_SIM_OFF))[gid - PREP_WVSE] = 0.f;
    } else if (gid < PREP_END) {
        int n = gid - PREP_SIME;
        float b = 0.f;
        #pragma unroll
        for (int d = 0; d < 64; ++d) b += bkv[n * 128 + 64 + d];
        ((float*)(ws + WS_BVS_OFF))[n] = b;
    }
}

// ---------------- kernel 1: fused q/k projection + per-head dot (MFMA, counted-vmcnt pipeline) ----------------
// grid (x=h 16, y=mb 16), 512 threads = 8 waves: w = qk*4 + rm*2 + dw.
// Wave: full-K 32x32 projection tile (rows m0+rm*32.., d-cols dw*32.. of q or k for head h).
// Pairing Cq*Ck in epilogue only (full-K first — bilinear-exact, round-3 lesson).
// Pipeline: B 4-buf global_load_lds depth-2 + A 2-buf reg-staged depth-2, raw s_barrier,
// s_waitcnt vmcnt(6) steady state (never 0 in main loop).
__global__ __launch_bounds__(512) void gemm_sim_kernel(
        const float* __restrict__ qin, const float* __restrict__ kvin,
        const float* __restrict__ bq, const float* __restrict__ bkv,
        unsigned char* __restrict__ ws) {
    __shared__ alignas(16) unsigned short Bt[4][2][128][32];    // 64 KB [buf][ks][col][kk]
    __shared__ alignas(16) unsigned short At[2][2][2][64][32];  // 32 KB [buf][p][ks][row][kk]
    __shared__ alignas(16) float Cqs[2][2][32][32];             // 16 KB [rm][dw][row][d]

    const int t = threadIdx.x;
    const int w = t >> 6, l = t & 63;
    const int h = blockIdx.x, mb = blockIdx.y;
    const int m0 = mb * 64;
    const int qk = w >> 2, rm = (w >> 1) & 1, dw = w & 1;
    const int lrow = l & 15, lko = (l >> 4) * 8;
    const int cb = qk * 64 + dw * 32;

    const unsigned char* wtile0 = ws + WS_WBT_OFF + (size_t)h * (32 * 16384);
    float* sim = (float*)(ws + WS_SIM_OFF);
    unsigned short* at0 = &At[0][0][0][0][0];
    unsigned short* bt0 = &Bt[0][0][0][0];

    f32x4 acc[2][2];
    acc[0][0] = (f32x4)0.f; acc[0][1] = (f32x4)0.f;
    acc[1][0] = (f32x4)0.f; acc[1][1] = (f32x4)0.f;

    // A staging map: thread t -> (ks, row, kk-granule); 64-B LDS rows (conflict-free)
    const int aks = t >> 8, arow = (t >> 2) & 63, akkg = t & 3;
    const float* aq_src = qin  + (size_t)(m0 + arow) * 2048 + aks * 32 + akkg * 8;
    const float* ak_src = kvin + (size_t)(m0 + arow) * 2048 + aks * 32 + akkg * 8;
    const int awoff = aks * 2048 + arow * 32 + akkg * 8;   // elem offset within [p]-slab

#define STAGE_B(ktile, buf) do {                                                   \
    const unsigned char* _src = wtile0 + (size_t)(ktile) * 16384;                  \
    unsigned char* _dst = ((unsigned char*)bt0) + (buf) * 16384;                   \
    _Pragma("unroll")                                                              \
    for (int _jj = 0; _jj < 2; ++_jj) {                                            \
        int _lin = _jj * 512 + t;                                                  \
        __builtin_amdgcn_global_load_lds(                                          \
            (const AS1 unsigned int*)(const void*)(_src + _lin * 16),              \
            (AS3 unsigned int*)(void*)(_dst + _lin * 16), 16, 0, 0);               \
    } } while (0)

#define LOAD_A(ktile, q0, q1, k0, k1) do {                                         \
    const float* _q = aq_src + (ktile) * 64;                                       \
    const float* _k = ak_src + (ktile) * 64;                                       \
    q0 = *(const float4*)_q;  q1 = *(const float4*)(_q + 4);                       \
    k0 = *(const float4*)_k;  k1 = *(const float4*)(_k + 4); } while (0)

#define WRITE_A(buf, q0, q1, k0, k1) do {                                          \
    *(uint4*)(at0 + (buf) * 8192 + awoff)        = pack8(q0, q1);                  \
    *(uint4*)(at0 + (buf) * 8192 + 4096 + awoff) = pack8(k0, k1); } while (0)

#define COMPUTE(abuf, bbuf) do {                                                   \
    const unsigned short* _Ab = at0 + (abuf) * 8192 + qk * 4096;                   \
    const unsigned short* _Bb = bt0 + (bbuf) * 8192;                               \
    _Pragma("unroll")                                                              \
    for (int _ks = 0; _ks < 2; ++_ks) {                                            \
        bfrag8 _fa0 = *(const bfrag8*)(_Ab + _ks * 2048 + (rm * 32 + lrow) * 32 + lko);      \
        bfrag8 _fa1 = *(const bfrag8*)(_Ab + _ks * 2048 + (rm * 32 + 16 + lrow) * 32 + lko); \
        bfrag8 _fb0 = *(const bfrag8*)(_Bb + _ks * 4096 + (cb + lrow) * 32 + lko);           \
        bfrag8 _fb1 = *(const bfrag8*)(_Bb + _ks * 4096 + (cb + 16 + lrow) * 32 + lko);      \
        acc[0][0] = __builtin_amdgcn_mfma_f32_16x16x32_bf16(_fa0, _fb0, acc[0][0], 0, 0, 0); \
        acc[0][1] = __builtin_amdgcn_mfma_f32_16x16x32_bf16(_fa0, _fb1, acc[0][1], 0, 0, 0); \
        acc[1][0] = __builtin_amdgcn_mfma_f32_16x16x32_bf16(_fa1, _fb0, acc[1][0], 0, 0, 0); \
        acc[1][1] = __builtin_amdgcn_mfma_f32_16x16x32_bf16(_fa1, _fb1, acc[1][1], 0, 0, 0); \
    } } while (0)

    float4 s0q0, s0q1, s0k0, s0k1;   // reg set 0 (A data for even k-tiles)
    float4 s1q0, s1q1, s1k0, s1k1;   // reg set 1 (odd)

    // ---- prologue: stage B(0),B(1); load A(0)->set0, A(1)->set1; write A(0)->At[0] ----
    STAGE_B(0, 0);
    STAGE_B(1, 1);
    LOAD_A(0, s0q0, s0q1, s0k0, s0k1);
    LOAD_A(1, s1q0, s1q1, s1k0, s1k1);
    WRITE_A(0, s0q0, s0q1, s0k0, s0k1);       // compiler auto-waits the A(0) loads

    // ---- main loop: 32 k-tiles, one barrier each, loads span 2 iters (vmcnt(6)) ----
    for (int ii = 0; ii < 8; ++ii) {
        #pragma unroll
        for (int u = 0; u < 4; ++u) {
            const int j = ii * 4 + u;
            // (a) issue next-next stage: B(j+2) dma, A(j+2) -> reg set j%2
            if (j < 30) {
                STAGE_B(j + 2, (u + 2) & 3);
                if ((u & 1) == 0) LOAD_A(j + 2, s0q0, s0q1, s0k0, s0k1);
                else              LOAD_A(j + 2, s1q0, s1q1, s1k0, s1k1);
            }
            // (b) LDS-write A(j+1) from reg set (j+1)%2 into At[(j+1)%2]
            if (j < 31) {
                if ((u & 1) == 0) WRITE_A((u + 1) & 1, s1q0, s1q1, s1k0, s1k1);
                else              WRITE_A((u + 1) & 1, s0q0, s0q1, s0k0, s0k1);
            }
            // (c) counted drain: B(j) landed (older than everything the waits leave)
            if (j < 30) asm volatile("s_waitcnt vmcnt(6)" ::: "memory");
            else        asm volatile("s_waitcnt vmcnt(0)" ::: "memory");
            asm volatile("s_waitcnt lgkmcnt(0)" ::: "memory");
            __builtin_amdgcn_sched_barrier(0);
            __builtin_amdgcn_s_barrier();
            __builtin_amdgcn_sched_barrier(0);
            // (d) compute k-tile j from At[j%2], Bt[j%4]
            COMPUTE(u & 1, u & 3);
        }
    }

    // ---- epilogue: +bias (fp32 exact), pair Cq*Ck, reduce over d, atomicAdd sim ----
    float biasv[2];
    #pragma unroll
    for (int ni = 0; ni < 2; ++ni) {
        int d = dw * 32 + ni * 16 + lrow;
        biasv[ni] = qk ? bkv[h * 128 + d] : bq[h * 64 + d];
    }
    #pragma unroll
    for (int mi = 0; mi < 2; ++mi)
        #pragma unroll
        for (int ni = 0; ni < 2; ++ni)
            #pragma unroll
            for (int r = 0; r < 4; ++r)
                acc[mi][ni][r] += biasv[ni];

    if (!qk) {
        #pragma unroll
        for (int mi = 0; mi < 2; ++mi)
            #pragma unroll
            for (int ni = 0; ni < 2; ++ni)
                #pragma unroll
                for (int r = 0; r < 4; ++r)
                    Cqs[rm][dw][mi * 16 + (l >> 4) * 4 + r][ni * 16 + lrow] = acc[mi][ni][r];
    }
    __syncthreads();
    if (qk) {
        #pragma unroll
        for (int mi = 0; mi < 2; ++mi) {
            float p[4];
            #pragma unroll
            for (int r = 0; r < 4; ++r) {
                int r32 = mi * 16 + (l >> 4) * 4 + r;
                p[r] = Cqs[rm][dw][r32][lrow]      * acc[mi][0][r]
                     + Cqs[rm][dw][r32][16 + lrow] * acc[mi][1][r];
            }
            #pragma unroll
            for (int r = 0; r < 4; ++r) {
                float v = p[r];
                v += __shfl_xor(v, 1); v += __shfl_xor(v, 2);
                v += __shfl_xor(v, 4); v += __shfl_xor(v, 8);
                if ((l & 15) == 0) {
                    int row = m0 + rm * 32 + mi * 16 + (l >> 4) * 4 + r;
                    atomicAdd(&sim[row * 16 + h], v);   // 2 adds/cell (dw halves)
                }
            }
        }
    }
#undef STAGE_B
#undef LOAD_A
#undef WRITE_A
#undef COMPUTE
}

// ---------------- kernel 2: S[b][n] = kv_input[b]·WvS[:,n] + bvS[n] (fp32) ----------------
__global__ __launch_bounds__(256) void s_kernel(
        const float* __restrict__ kvin, unsigned char* __restrict__ ws) {
    int b = blockIdx.x, t = threadIdx.x;
    int w = t >> 6, l = t & 63;
    __shared__ float SW[4][16];
    int n = t & 15, g = t >> 4;
    const float* kvrow = kvin + (size_t)b * 2048;
    const float* wv = (const float*)(ws + WS_WVS_OFF);
    float p = 0.f;
    #pragma unroll 4
    for (int tt = 0; tt < 128; ++tt) {
        int c = g + (tt << 4);
        p = fmaf(kvrow[c], wv[c * 16 + n], p);
    }
    p += __shfl_xor(p, 16);
    p += __shfl_xor(p, 32);
    if (l < 16) SW[w][n] = p;
    __syncthreads();
    if (t < 16) {
        float sv = SW[0][t] + SW[1][t] + SW[2][t] + SW[3][t]
                 + ((const float*)(ws + WS_BVS_OFF))[t];
        ((float*)(ws + WS_S_OFF))[b * 16 + t] = sv;
    }
}

// ---------------- kernel 3: softmax, A-reduce, pooled, leaky, batchnorm, output ----------------
__global__ __launch_bounds__(1024) void final_kernel(
        const float* __restrict__ bn_w, const float* __restrict__ bn_b,
        const float* __restrict__ Wo, const float* __restrict__ bo,
        const unsigned char* __restrict__ ws, float* __restrict__ out) {
    int t = threadIdx.x;
    int w = t >> 6;
    int l = t & 63;
    __shared__ float Aw[16][16];
    __shared__ float Af[4][16];
    __shared__ float SWs[16][8];
    __shared__ float FS[8];
    __shared__ float sc[4], sh[4];

    float a16[16];
    {
        const float* srow = (const float*)(ws + WS_SIM_OFF) + (size_t)t * 16;
        float4 v0 = *(const float4*)(srow + 0);
        float4 v1 = *(const float4*)(srow + 4);
        float4 v2 = *(const float4*)(srow + 8);
        float4 v3 = *(const float4*)(srow + 12);
        a16[0]=v0.x; a16[1]=v0.y; a16[2]=v0.z; a16[3]=v0.w;
        a16[4]=v1.x; a16[5]=v1.y; a16[6]=v1.z; a16[7]=v1.w;
        a16[8]=v2.x; a16[9]=v2.y; a16[10]=v2.z; a16[11]=v2.w;
        a16[12]=v3.x; a16[13]=v3.y; a16[14]=v3.z; a16[15]=v3.w;
        float m = a16[0];
        #pragma unroll
        for (int n = 1; n < 16; ++n) m = fmaxf(m, a16[n]);
        float den = 0.f;
        #pragma unroll
        for (int n = 0; n < 16; ++n) { a16[n] = expf(a16[n] - m); den += a16[n]; }
        float inv = 1.f / den;
        #pragma unroll
        for (int n = 0; n < 16; ++n) a16[n] *= inv;
    }
    #pragma unroll
    for (int n = 0; n < 16; ++n) {
        float p = a16[n];
        p += __shfl_xor(p, 1);  p += __shfl_xor(p, 2);
        p += __shfl_xor(p, 4);  p += __shfl_xor(p, 8);
        p += __shfl_xor(p, 16); p += __shfl_xor(p, 32);
        a16[n] = p;
    }
    if (l == 0) {
        #pragma unroll
        for (int n = 0; n < 16; ++n) Aw[w][n] = a16[n];
    }
    __syncthreads();
    if (t < 64) {
        int f = t >> 4, n = t & 15;
        Af[f][n] = Aw[4*f][n] + Aw[4*f+1][n] + Aw[4*f+2][n] + Aw[4*f+3][n];
    }
    __syncthreads();

    float sv[16];
    {
        const float* srow = (const float*)(ws + WS_S_OFF) + (size_t)t * 16;
        float4 v0 = *(const float4*)(srow + 0);
        float4 v1 = *(const float4*)(srow + 4);
        float4 v2 = *(const float4*)(srow + 8);
        float4 v3 = *(const float4*)(srow + 12);
        sv[0]=v0.x; sv[1]=v0.y; sv[2]=v0.z; sv[3]=v0.w;
        sv[4]=v1.x; sv[5]=v1.y; sv[6]=v1.z; sv[7]=v1.w;
        sv[8]=v2.x; sv[9]=v2.y; sv[10]=v2.z; sv[11]=v2.w;
        sv[12]=v3.x; sv[13]=v3.y; sv[14]=v3.z; sv[15]=v3.w;
    }
    float x[4];
    #pragma unroll
    for (int f = 0; f < 4; ++f) {
        float p = 0.f;
        #pragma unroll
        for (int n = 0; n < 16; ++n) p = fmaf(Af[f][n], sv[n], p);
        p *= (1.f / 16384.f);
        x[f] = (p >= 0.f) ? p : SLOPE * p;
    }

    float st[8];
    #pragma unroll
    for (int f = 0; f < 4; ++f) { st[f] = x[f]; st[4 + f] = x[f] * x[f]; }
    #pragma unroll
    for (int j = 0; j < 8; ++j) {
        float p = st[j];
        p += __shfl_xor(p, 1);  p += __shfl_xor(p, 2);
        p += __shfl_xor(p, 4);  p += __shfl_xor(p, 8);
        p += __shfl_xor(p, 16); p += __shfl_xor(p, 32);
        st[j] = p;
    }
    if (l == 0) {
        #pragma unroll
        for (int j = 0; j < 8; ++j) SWs[w][j] = st[j];
    }
    __syncthreads();
    if (t < 8) {
        float p = 0.f;
        #pragma unroll
        for (int ww = 0; ww < 16; ++ww) p += SWs[ww][t];
        FS[t] = p;
    }
    __syncthreads();
    if (t < 4) {
        float mean = FS[t] * (1.f / 1024.f);
        float var  = FS[4 + t] * (1.f / 1024.f) - mean * mean;
        float s = bn_w[t] / sqrtf(var + EPS);
        sc[t] = s;
        sh[t] = bn_b[t] - mean * s;
    }
    __syncthreads();

    float o0 = bo[0], o1 = bo[1];
    #pragma unroll
    for (int f = 0; f < 4; ++f) {
        float xh = x[f] * sc[f] + sh[f];
        o0 = fmaf(xh, Wo[f], o0);
        o1 = fmaf(xh, Wo[4 + f], o1);
    }
    *(float2*)(out + (size_t)t * 2) = make_float2(o0, o1);
}

// ---------------- launch ----------------
extern "C" void kernel_launch(void* const* d_in, const int* in_sizes, int n_in,
                              void* d_out, int out_size, void* d_ws, size_t ws_size,
                              hipStream_t stream) {
    const float* q_input  = (const float*)d_in[0];
    const float* kv_input = (const float*)d_in[1];
    const float* Wq   = (const float*)d_in[2];
    const float* bq   = (const float*)d_in[3];
    const float* Wkv  = (const float*)d_in[4];
    const float* bkv  = (const float*)d_in[5];
    const float* bn_w = (const float*)d_in[6];
    const float* bn_b = (const float*)d_in[7];
    const float* Wo   = (const float*)d_in[8];
    const float* bo   = (const float*)d_in[9];
    float* out = (float*)d_out;
    unsigned char* ws = (unsigned char*)d_ws;

    hipLaunchKernelGGL(prep_kernel, dim3((PREP_END + 255) / 256), dim3(256), 0, stream,
                       Wq, bq, Wkv, bkv, ws);
    hipLaunchKernelGGL(gemm_sim_kernel, dim3(16, 16), dim3(512), 0, stream,
                       q_input, kv_input, bq, bkv, ws);
    hipLaunchKernelGGL(s_kernel, dim3(1024), dim3(256), 0, stream, kv_input, ws);
    hipLaunchKernelGGL(final_kernel, dim3(1), dim3(1024), 0, stream,
                       bn_w, bn_b, Wo, bo, ws, out);
}

// Round 7
// 66.587 us; speedup vs baseline: 2.7101x; 1.0156x over previous
//
#include <hip/hip_runtime.h>
#include <hip/hip_bf16.h>

#define EPS 1e-5f
#define SLOPE 0.01f

typedef __attribute__((ext_vector_type(8))) short bfrag8;   // 8 bf16 (4 VGPRs)
typedef __attribute__((ext_vector_type(4))) float f32x4;

// ---- workspace byte offsets ----
#define WS_SIM_OFF   0u          // [1024][16] f32 (zeroed by prep)
#define WS_S_OFF     65536u      // [1024][16] f32
#define WS_WVS_OFF   131072u     // [2048][16] f32, transposed [c][n]
#define WS_BVS_OFF   262144u     // [16] f32
#define WS_AIMG_OFF  262208u     // bf16 A image, fragment-ordered: [qk2][mb16][rm2][kt32][ks2][mi2][lane64][8e] = 8,388,608 B
#define WS_BIMG_OFF  8650816u    // bf16 B image, fragment-ordered: [h16][qk2][dw2][kt32][ks2][ni2][lane64][8e] = 8,388,608 B

// round-to-nearest-even fp32 -> bf16
__device__ __forceinline__ unsigned short f2bf(float f) {
    union { float f; unsigned int u; } x; x.f = f;
    unsigned int r = (x.u + 0x7FFFu + ((x.u >> 16) & 1u)) >> 16;
    return (unsigned short)r;
}
__device__ __forceinline__ uint4 pack8(const float4& a, const float4& b) {
    uint4 r;
    r.x = (unsigned)f2bf(a.x) | ((unsigned)f2bf(a.y) << 16);
    r.y = (unsigned)f2bf(a.z) | ((unsigned)f2bf(a.w) << 16);
    r.z = (unsigned)f2bf(b.x) | ((unsigned)f2bf(b.y) << 16);
    r.w = (unsigned)f2bf(b.z) | ((unsigned)f2bf(b.w) << 16);
    return r;
}

// ---------------- kernel 0: prep — build fragment-ordered bf16 images ----------------
// One thread per 16-B image granule. Fragment layout (m92-verified): lane l holds
// [row/col = l&15][k = (l>>4)*8 .. +8], so gemm loads are base + l*16, coalesced 1 KB.
#define PREP_A   524288
#define PREP_B2  (PREP_A + 524288)
#define PREP_WVSE (PREP_B2 + 32768)
#define PREP_SIME (PREP_WVSE + 16384)
#define PREP_END  (PREP_SIME + 16)

__global__ __launch_bounds__(256) void prep_kernel(
        const float* __restrict__ qin, const float* __restrict__ kvin,
        const float* __restrict__ Wq, const float* __restrict__ Wkv,
        const float* __restrict__ bkv, unsigned char* __restrict__ ws) {
    int gid = blockIdx.x * 256 + threadIdx.x;
    if (gid < PREP_A) {
        // A image granule: [qk][mb][rm][kt][ks][mi][lane]
        int l  = gid & 63;
        int mi = (gid >> 6) & 1;
        int ks = (gid >> 7) & 1;
        int kt = (gid >> 8) & 31;
        int rm = (gid >> 13) & 1;
        int mbb = (gid >> 14) & 15;
        int qq = gid >> 18;
        int row = mbb * 64 + rm * 32 + mi * 16 + (l & 15);
        int k0  = kt * 64 + ks * 32 + (l >> 4) * 8;
        const float* src = (qq ? kvin : qin) + (size_t)row * 2048 + k0;
        float4 v0 = *(const float4*)src;
        float4 v1 = *(const float4*)(src + 4);
        *(uint4*)(ws + WS_AIMG_OFF + (size_t)gid * 16) = pack8(v0, v1);
    } else if (gid < PREP_B2) {
        // B image granule: [h][qk][dw][kt][ks][ni][lane]
        int g2 = gid - PREP_A;
        int l  = g2 & 63;
        int ni = (g2 >> 6) & 1;
        int ks = (g2 >> 7) & 1;
        int kt = (g2 >> 8) & 31;
        int dww = (g2 >> 13) & 1;
        int qq  = (g2 >> 14) & 1;
        int hh  = g2 >> 15;
        int col = qq * 64 + dww * 32 + ni * 16 + (l & 15);
        int k0  = kt * 64 + ks * 32 + (l >> 4) * 8;
        const float* wrow = (col < 64) ? (Wq  + (size_t)(hh * 64 + col) * 2048)
                                       : (Wkv + (size_t)(hh * 128 + (col - 64)) * 2048);
        float4 v0 = *(const float4*)(wrow + k0);
        float4 v1 = *(const float4*)(wrow + k0 + 4);
        *(uint4*)(ws + WS_BIMG_OFF + (size_t)g2 * 16) = pack8(v0, v1);
    } else if (gid < PREP_WVSE) {
        int g2 = gid - PREP_B2;
        int n = g2 >> 11, c = g2 & 2047;
        const float* base = Wkv + (size_t)(n * 128 + 64) * 2048 + c;
        float s = 0.f;
        #pragma unroll 8
        for (int d = 0; d < 64; ++d) s += base[(size_t)d * 2048];
        ((float*)(ws + WS_WVS_OFF))[c * 16 + n] = s;
    } else if (gid < PREP_SIME) {
        ((float*)(ws + WS_SIM_OFF))[gid - PREP_WVSE] = 0.f;
    } else if (gid < PREP_END) {
        int n = gid - PREP_SIME;
        float b = 0.f;
        #pragma unroll
        for (int d = 0; d < 64; ++d) b += bkv[n * 128 + 64 + d];
        ((float*)(ws + WS_BVS_OFF))[n] = b;
    }
}

// ---------------- kernel 1: fused q/k projection + per-head dot ----------------
// grid (x=h 16, y=mb 16), 512 threads = 8 waves: w = qk*4 + rm*2 + dw.
// NO LDS / NO barriers in the main loop: both operands arrive as coalesced
// global_load_dwordx4 from fragment-ordered images; depth-2 register pipeline
// (3 named sets — rule 20: all indices compile-time); compiler inserts exact vmcnt.
// Full-K accumulated per-wave before pairing (bilinear-exact, round-3 lesson);
// epilogue pairing via 16 KB LDS + single barrier (round-6-verified).
__global__ __launch_bounds__(512) void gemm_sim_kernel(
        const float* __restrict__ bq, const float* __restrict__ bkv,
        unsigned char* __restrict__ ws) {
    __shared__ alignas(16) float Cqs[2][2][32][32];   // 16 KB [rm][dw][row][d]

    const int t = threadIdx.x;
    const int w = t >> 6, l = t & 63;
    const int h = blockIdx.x, mb = blockIdx.y;
    const int m0 = mb * 64;
    const int qk = w >> 2, rm = (w >> 1) & 1, dw = w & 1;
    const int lrow = l & 15;

    const unsigned char* aP = ws + WS_AIMG_OFF
        + (size_t)(((qk * 16 + mb) * 2 + rm) * 32) * 4096 + l * 16;
    const unsigned char* bP = ws + WS_BIMG_OFF
        + (size_t)(((h * 2 + qk) * 2 + dw) * 32) * 4096 + l * 16;
    float* sim = (float*)(ws + WS_SIM_OFF);

    f32x4 acc00 = (f32x4)0.f, acc01 = (f32x4)0.f, acc10 = (f32x4)0.f, acc11 = (f32x4)0.f;

    // frag naming: {set}a{ks}{mi}, {set}b{ks}{ni}; image in-tile offsets = ks*2048 + (mi|ni)*1024
#define DECL_SET(S) bfrag8 S##a00, S##a01, S##a10, S##a11, S##b00, S##b01, S##b10, S##b11
#define LOADS(kt, S) do {                                                     \
    const unsigned char* _a = aP + (size_t)(kt) * 4096;                       \
    const unsigned char* _b = bP + (size_t)(kt) * 4096;                       \
    S##a00 = *(const bfrag8*)(_a);                                            \
    S##a01 = *(const bfrag8*)(_a + 1024);                                     \
    S##a10 = *(const bfrag8*)(_a + 2048);                                     \
    S##a11 = *(const bfrag8*)(_a + 3072);                                     \
    S##b00 = *(const bfrag8*)(_b);                                            \
    S##b01 = *(const bfrag8*)(_b + 1024);                                     \
    S##b10 = *(const bfrag8*)(_b + 2048);                                     \
    S##b11 = *(const bfrag8*)(_b + 3072);                                     \
} while (0)
#define COMP(S) do {                                                                        \
    acc00 = __builtin_amdgcn_mfma_f32_16x16x32_bf16(S##a00, S##b00, acc00, 0, 0, 0);        \
    acc01 = __builtin_amdgcn_mfma_f32_16x16x32_bf16(S##a00, S##b01, acc01, 0, 0, 0);        \
    acc10 = __builtin_amdgcn_mfma_f32_16x16x32_bf16(S##a01, S##b00, acc10, 0, 0, 0);        \
    acc11 = __builtin_amdgcn_mfma_f32_16x16x32_bf16(S##a01, S##b01, acc11, 0, 0, 0);        \
    acc00 = __builtin_amdgcn_mfma_f32_16x16x32_bf16(S##a10, S##b10, acc00, 0, 0, 0);        \
    acc01 = __builtin_amdgcn_mfma_f32_16x16x32_bf16(S##a10, S##b11, acc01, 0, 0, 0);        \
    acc10 = __builtin_amdgcn_mfma_f32_16x16x32_bf16(S##a11, S##b10, acc10, 0, 0, 0);        \
    acc11 = __builtin_amdgcn_mfma_f32_16x16x32_bf16(S##a11, S##b11, acc11, 0, 0, 0);        \
} while (0)

    DECL_SET(P0_); DECL_SET(P1_); DECL_SET(P2_);
    LOADS(0, P0_);
    LOADS(1, P1_);
    // rotation invariant entering body at kt: P0 = tile kt, P1 = tile kt+1
    for (int kt = 0; kt < 30; kt += 3) {
        LOADS(kt + 2, P2_);  COMP(P0_);
        LOADS(kt + 3, P0_);  COMP(P1_);
        LOADS(kt + 4, P1_);  COMP(P2_);
    }
    COMP(P0_);   // tile 30
    COMP(P1_);   // tile 31
#undef DECL_SET
#undef LOADS
#undef COMP

    // ---- epilogue: +bias (fp32 exact), pair Cq*Ck, reduce over d, atomicAdd sim ----
    float biasv[2];
    #pragma unroll
    for (int ni = 0; ni < 2; ++ni) {
        int d = dw * 32 + ni * 16 + lrow;
        biasv[ni] = qk ? bkv[h * 128 + d] : bq[h * 64 + d];
    }
    f32x4 acc[2][2] = {{acc00, acc01}, {acc10, acc11}};
    #pragma unroll
    for (int mi = 0; mi < 2; ++mi)
        #pragma unroll
        for (int ni = 0; ni < 2; ++ni)
            #pragma unroll
            for (int r = 0; r < 4; ++r)
                acc[mi][ni][r] += biasv[ni];

    if (!qk) {
        #pragma unroll
        for (int mi = 0; mi < 2; ++mi)
            #pragma unroll
            for (int ni = 0; ni < 2; ++ni)
                #pragma unroll
                for (int r = 0; r < 4; ++r)
                    Cqs[rm][dw][mi * 16 + (l >> 4) * 4 + r][ni * 16 + lrow] = acc[mi][ni][r];
    }
    __syncthreads();
    if (qk) {
        #pragma unroll
        for (int mi = 0; mi < 2; ++mi) {
            float p[4];
            #pragma unroll
            for (int r = 0; r < 4; ++r) {
                int r32 = mi * 16 + (l >> 4) * 4 + r;
                p[r] = Cqs[rm][dw][r32][lrow]      * acc[mi][0][r]
                     + Cqs[rm][dw][r32][16 + lrow] * acc[mi][1][r];
            }
            #pragma unroll
            for (int r = 0; r < 4; ++r) {
                float v = p[r];
                v += __shfl_xor(v, 1); v += __shfl_xor(v, 2);
                v += __shfl_xor(v, 4); v += __shfl_xor(v, 8);
                if ((l & 15) == 0) {
                    int row = m0 + rm * 32 + mi * 16 + (l >> 4) * 4 + r;
                    atomicAdd(&sim[row * 16 + h], v);   // 2 adds/cell (dw halves)
                }
            }
        }
    }
}

// ---------------- kernel 2: S[b][n] = kv_input[b]·WvS[:,n] + bvS[n] (fp32) ----------------
__global__ __launch_bounds__(256) void s_kernel(
        const float* __restrict__ kvin, unsigned char* __restrict__ ws) {
    int b = blockIdx.x, t = threadIdx.x;
    int w = t >> 6, l = t & 63;
    __shared__ float SW[4][16];
    int n = t & 15, g = t >> 4;
    const float* kvrow = kvin + (size_t)b * 2048;
    const float* wv = (const float*)(ws + WS_WVS_OFF);
    float p = 0.f;
    #pragma unroll 4
    for (int tt = 0; tt < 128; ++tt) {
        int c = g + (tt << 4);
        p = fmaf(kvrow[c], wv[c * 16 + n], p);
    }
    p += __shfl_xor(p, 16);
    p += __shfl_xor(p, 32);
    if (l < 16) SW[w][n] = p;
    __syncthreads();
    if (t < 16) {
        float sv = SW[0][t] + SW[1][t] + SW[2][t] + SW[3][t]
                 + ((const float*)(ws + WS_BVS_OFF))[t];
        ((float*)(ws + WS_S_OFF))[b * 16 + t] = sv;
    }
}

// ---------------- kernel 3: softmax, A-reduce, pooled, leaky, batchnorm, output ----------------
__global__ __launch_bounds__(1024) void final_kernel(
        const float* __restrict__ bn_w, const float* __restrict__ bn_b,
        const float* __restrict__ Wo, const float* __restrict__ bo,
        const unsigned char* __restrict__ ws, float* __restrict__ out) {
    int t = threadIdx.x;
    int w = t >> 6;
    int l = t & 63;
    __shared__ float Aw[16][16];
    __shared__ float Af[4][16];
    __shared__ float SWs[16][8];
    __shared__ float FS[8];
    __shared__ float sc[4], sh[4];

    float a16[16];
    {
        const float* srow = (const float*)(ws + WS_SIM_OFF) + (size_t)t * 16;
        float4 v0 = *(const float4*)(srow + 0);
        float4 v1 = *(const float4*)(srow + 4);
        float4 v2 = *(const float4*)(srow + 8);
        float4 v3 = *(const float4*)(srow + 12);
        a16[0]=v0.x; a16[1]=v0.y; a16[2]=v0.z; a16[3]=v0.w;
        a16[4]=v1.x; a16[5]=v1.y; a16[6]=v1.z; a16[7]=v1.w;
        a16[8]=v2.x; a16[9]=v2.y; a16[10]=v2.z; a16[11]=v2.w;
        a16[12]=v3.x; a16[13]=v3.y; a16[14]=v3.z; a16[15]=v3.w;
        float m = a16[0];
        #pragma unroll
        for (int n = 1; n < 16; ++n) m = fmaxf(m, a16[n]);
        float den = 0.f;
        #pragma unroll
        for (int n = 0; n < 16; ++n) { a16[n] = expf(a16[n] - m); den += a16[n]; }
        float inv = 1.f / den;
        #pragma unroll
        for (int n = 0; n < 16; ++n) a16[n] *= inv;
    }
    #pragma unroll
    for (int n = 0; n < 16; ++n) {
        float p = a16[n];
        p += __shfl_xor(p, 1);  p += __shfl_xor(p, 2);
        p += __shfl_xor(p, 4);  p += __shfl_xor(p, 8);
        p += __shfl_xor(p, 16); p += __shfl_xor(p, 32);
        a16[n] = p;
    }
    if (l == 0) {
        #pragma unroll
        for (int n = 0; n < 16; ++n) Aw[w][n] = a16[n];
    }
    __syncthreads();
    if (t < 64) {
        int f = t >> 4, n = t & 15;
        Af[f][n] = Aw[4*f][n] + Aw[4*f+1][n] + Aw[4*f+2][n] + Aw[4*f+3][n];
    }
    __syncthreads();

    float sv[16];
    {
        const float* srow = (const float*)(ws + WS_S_OFF) + (size_t)t * 16;
        float4 v0 = *(const float4*)(srow + 0);
        float4 v1 = *(const float4*)(srow + 4);
        float4 v2 = *(const float4*)(srow + 8);
        float4 v3 = *(const float4*)(srow + 12);
        sv[0]=v0.x; sv[1]=v0.y; sv[2]=v0.z; sv[3]=v0.w;
        sv[4]=v1.x; sv[5]=v1.y; sv[6]=v1.z; sv[7]=v1.w;
        sv[8]=v2.x; sv[9]=v2.y; sv[10]=v2.z; sv[11]=v2.w;
        sv[12]=v3.x; sv[13]=v3.y; sv[14]=v3.z; sv[15]=v3.w;
    }
    float x[4];
    #pragma unroll
    for (int f = 0; f < 4; ++f) {
        float p = 0.f;
        #pragma unroll
        for (int n = 0; n < 16; ++n) p = fmaf(Af[f][n], sv[n], p);
        p *= (1.f / 16384.f);
        x[f] = (p >= 0.f) ? p : SLOPE * p;
    }

    float st[8];
    #pragma unroll
    for (int f = 0; f < 4; ++f) { st[f] = x[f]; st[4 + f] = x[f] * x[f]; }
    #pragma unroll
    for (int j = 0; j < 8; ++j) {
        float p = st[j];
        p += __shfl_xor(p, 1);  p += __shfl_xor(p, 2);
        p += __shfl_xor(p, 4);  p += __shfl_xor(p, 8);
        p += __shfl_xor(p, 16); p += __shfl_xor(p, 32);
        st[j] = p;
    }
    if (l == 0) {
        #pragma unroll
        for (int j = 0; j < 8; ++j) SWs[w][j] = st[j];
    }
    __syncthreads();
    if (t < 8) {
        float p = 0.f;
        #pragma unroll
        for (int ww = 0; ww < 16; ++ww) p += SWs[ww][t];
        FS[t] = p;
    }
    __syncthreads();
    if (t < 4) {
        float mean = FS[t] * (1.f / 1024.f);
        float var  = FS[4 + t] * (1.f / 1024.f) - mean * mean;
        float s = bn_w[t] / sqrtf(var + EPS);
        sc[t] = s;
        sh[t] = bn_b[t] - mean * s;
    }
    __syncthreads();

    float o0 = bo[0], o1 = bo[1];
    #pragma unroll
    for (int f = 0; f < 4; ++f) {
        float xh = x[f] * sc[f] + sh[f];
        o0 = fmaf(xh, Wo[f], o0);
        o1 = fmaf(xh, Wo[4 + f], o1);
    }
    *(float2*)(out + (size_t)t * 2) = make_float2(o0, o1);
}

// ---------------- launch ----------------
extern "C" void kernel_launch(void* const* d_in, const int* in_sizes, int n_in,
                              void* d_out, int out_size, void* d_ws, size_t ws_size,
                              hipStream_t stream) {
    const float* q_input  = (const float*)d_in[0];
    const float* kv_input = (const float*)d_in[1];
    const float* Wq   = (const float*)d_in[2];
    const float* bq   = (const float*)d_in[3];
    const float* Wkv  = (const float*)d_in[4];
    const float* bkv  = (const float*)d_in[5];
    const float* bn_w = (const float*)d_in[6];
    const float* bn_b = (const float*)d_in[7];
    const float* Wo   = (const float*)d_in[8];
    const float* bo   = (const float*)d_in[9];
    float* out = (float*)d_out;
    unsigned char* ws = (unsigned char*)d_ws;

    hipLaunchKernelGGL(prep_kernel, dim3((PREP_END + 255) / 256), dim3(256), 0, stream,
                       q_input, kv_input, Wq, Wkv, bkv, ws);
    hipLaunchKernelGGL(gemm_sim_kernel, dim3(16, 16), dim3(512), 0, stream,
                       bq, bkv, ws);
    hipLaunchKernelGGL(s_kernel, dim3(1024), dim3(256), 0, stream, kv_input, ws);
    hipLaunchKernelGGL(final_kernel, dim3(1), dim3(1024), 0, stream,
                       bn_w, bn_b, Wo, bo, ws, out);
}